// Round 7
// baseline (2729.410 us; speedup 1.0000x reference)
//
#include <hip/hip_runtime.h>
#include <math.h>

#define BB 128
#define NN 256
#define DD 64
constexpr int NROWS = BB * NN; // 32768

// ---------------- 1. L2 normalize (one wave per row of 64) ----------------
__global__ __launch_bounds__(256) void norm_kernel(const float* __restrict__ inp,
                                                   const float* __restrict__ tgin,
                                                   float* __restrict__ ipn,
                                                   float* __restrict__ tgn) {
  int wid = threadIdx.x >> 6;
  int lane = threadIdx.x & 63;
  int row = blockIdx.x * 4 + wid;   // 0 .. 2*NROWS-1
  const float* src;
  float* dst;
  int r = row;
  if (row < NROWS) { src = inp; dst = ipn; }
  else { src = tgin; dst = tgn; r = row - NROWS; }
  float x = src[(size_t)r * DD + lane];
  float s = x * x;
  #pragma unroll
  for (int off = 32; off; off >>= 1) s += __shfl_xor(s, off);
  float nrm = sqrtf(s);
  float scale = 1.0f / fmaxf(nrm, 1e-12f);
  dst[(size_t)r * DD + lane] = x * scale;
}

// ---------------- 2. batched fp32 GEMM: 64x64 tile, K=64 ----------------
__global__ __launch_bounds__(256) void gemm_kernel(const float* __restrict__ ipn,
                                                   const float* __restrict__ tgn,
                                                   float* __restrict__ cosm,
                                                   float* __restrict__ selfm) {
  __shared__ float As[64 * 64];  // [k][row] transposed
  __shared__ float Bs[64 * 64];
  int b = blockIdx.y;
  int ti = (blockIdx.x >> 2) * 64;
  int tj = (blockIdx.x & 3) * 64;
  const float* A = ipn + (size_t)b * NN * DD + (size_t)ti * DD;
  const float* Bm = (blockIdx.z ? ipn : tgn) + (size_t)b * NN * DD + (size_t)tj * DD;
  float* Out = (blockIdx.z ? selfm : cosm) + (size_t)b * NN * NN;
  int t = threadIdx.x;
  #pragma unroll
  for (int i = 0; i < 4; ++i) {
    int f4 = t + 256 * i;
    int row = f4 >> 4;
    int k0 = (f4 & 15) << 2;
    float4 a = reinterpret_cast<const float4*>(A)[f4];
    float4 v = reinterpret_cast<const float4*>(Bm)[f4];
    As[(k0 + 0) * 64 + row] = a.x; As[(k0 + 1) * 64 + row] = a.y;
    As[(k0 + 2) * 64 + row] = a.z; As[(k0 + 3) * 64 + row] = a.w;
    Bs[(k0 + 0) * 64 + row] = v.x; Bs[(k0 + 1) * 64 + row] = v.y;
    Bs[(k0 + 2) * 64 + row] = v.z; Bs[(k0 + 3) * 64 + row] = v.w;
  }
  __syncthreads();
  int tx = t & 15, ty = t >> 4;
  float acc[4][4] = {};
  #pragma unroll 8
  for (int k = 0; k < 64; ++k) {
    float4 av = *reinterpret_cast<const float4*>(&As[k * 64 + ty * 4]);
    float4 bv = *reinterpret_cast<const float4*>(&Bs[k * 64 + tx * 4]);
    float ar[4] = {av.x, av.y, av.z, av.w};
    float br[4] = {bv.x, bv.y, bv.z, bv.w};
    #pragma unroll
    for (int r = 0; r < 4; ++r)
      #pragma unroll
      for (int c = 0; c < 4; ++c)
        acc[r][c] = fmaf(ar[r], br[c], acc[r][c]);
  }
  #pragma unroll
  for (int r = 0; r < 4; ++r) {
    float4 o = {acc[r][0], acc[r][1], acc[r][2], acc[r][3]};
    *reinterpret_cast<float4*>(&Out[(size_t)(ti + ty * 4 + r) * NN + tj + tx * 4]) = o;
  }
}

// ---------------- 3. LAPJV: CR + ARR init, then Dijkstra (one wave/batch) ----------------
__device__ __forceinline__ int sel4i(const int a[4], int q) {
  int r = a[0];
  if (q == 1) r = a[1];
  else if (q == 2) r = a[2];
  else if (q == 3) r = a[3];
  return r;
}
__device__ __forceinline__ void set4i(int a[4], int q, int v) {
  if (q == 0) a[0] = v;
  else if (q == 1) a[1] = v;
  else if (q == 2) a[2] = v;
  else a[3] = v;
}
__device__ __forceinline__ int readlane_i(int x, int l) {
  return __builtin_amdgcn_readlane(x, l);
}
// 64-lane unsigned min via DPP; global min lands in lane 63.
__device__ __forceinline__ unsigned wave_min_u32(unsigned x) {
  unsigned t;
  #define DPP_STEP(ctrl)                                                        \
    t = (unsigned)__builtin_amdgcn_update_dpp((int)x, (int)x, ctrl, 0xF, 0xF,   \
                                              false);                           \
    x = (t < x) ? t : x;
  DPP_STEP(0x111)  // row_shr:1
  DPP_STEP(0x112)  // row_shr:2
  DPP_STEP(0x114)  // row_shr:4
  DPP_STEP(0x118)  // row_shr:8
  DPP_STEP(0x142)  // row_bcast:15
  DPP_STEP(0x143)  // row_bcast:31
  #undef DPP_STEP
  return x;
}
// deterministic compaction of {i : x[i] < 0} into Fl; returns count
__device__ __forceinline__ int compact_free(const int* x_lds, int* Fl, int lane) {
  int row0 = lane * 4;
  int4 xv = *reinterpret_cast<const int4*>(&x_lds[row0]);
  int f0 = (xv.x < 0), f1 = (xv.y < 0), f2 = (xv.z < 0), f3 = (xv.w < 0);
  int cnt = f0 + f1 + f2 + f3;
  int sc = cnt;
  #pragma unroll
  for (int off = 1; off < 64; off <<= 1) {
    int t = __shfl_up(sc, off);
    if (lane >= off) sc += t;
  }
  int pos = sc - cnt;  // exclusive prefix
  if (f0) { Fl[pos] = row0 + 0; pos++; }
  if (f1) { Fl[pos] = row0 + 1; pos++; }
  if (f2) { Fl[pos] = row0 + 2; pos++; }
  if (f3) { Fl[pos] = row0 + 3; pos++; }
  return readlane_i(sc, 63);
}

__global__ __launch_bounds__(64) void hungarian_kernel(const float* __restrict__ cosm,
                                                       int* __restrict__ tgt) {
  const int b = blockIdx.x;
  const float* __restrict__ C = cosm + (size_t)b * NN * NN;
  __shared__ unsigned short Cs[NN * NN];  // 128 KiB u16 fixed-point cost
  __shared__ int u_lds[NN];               // row duals
  __shared__ int x_lds[NN];               // row -> col (-1 = free)
  __shared__ int claim[NN];               // CR claims; reused as v-broadcast
  __shared__ int Fl[1024];                // free-row worklist
  const int lane = threadIdx.x;           // 0..63
  const int col0 = lane * 4;

  // ---- stage: C_int = clamp(round((1 - cos) * 32768), 0, 65535) ----
  const float4* Cf4 = reinterpret_cast<const float4*>(C);
  #pragma unroll 4
  for (int it = 0; it < NN * NN / 4 / 64; ++it) {
    float4 f = Cf4[it * 64 + lane];
    unsigned u0 = __float2uint_rn(fmaxf(32768.f - f.x * 32768.f, 0.f));
    unsigned u1 = __float2uint_rn(fmaxf(32768.f - f.y * 32768.f, 0.f));
    unsigned u2 = __float2uint_rn(fmaxf(32768.f - f.z * 32768.f, 0.f));
    unsigned u3 = __float2uint_rn(fmaxf(32768.f - f.w * 32768.f, 0.f));
    u0 = u0 > 65535u ? 65535u : u0;
    u1 = u1 > 65535u ? 65535u : u1;
    u2 = u2 > 65535u ? 65535u : u2;
    u3 = u3 > 65535u ? 65535u : u3;
    uint2 packed;
    packed.x = u0 | (u1 << 16);
    packed.y = u2 | (u3 << 16);
    *reinterpret_cast<uint2*>(&Cs[(it * 64 + lane) * 4]) = packed;
  }
  {
    int4 mi = {-1, -1, -1, -1};
    *reinterpret_cast<int4*>(&x_lds[col0]) = mi;
    *reinterpret_cast<int4*>(&claim[col0]) = mi;
  }

  // ---- column reduction: v[j] = min_i c[i][j] (strict < => lowest row) ----
  int m0 = 0x7FFFFFFF, m1 = 0x7FFFFFFF, m2 = 0x7FFFFFFF, m3 = 0x7FFFFFFF;
  int a0 = 0, a1 = 0, a2 = 0, a3 = 0;
  #pragma unroll 4
  for (int i = 0; i < NN; ++i) {
    uint2 raw = *reinterpret_cast<const uint2*>(&Cs[(size_t)i * NN + col0]);
    int c0 = (int)(raw.x & 0xFFFFu), c1 = (int)(raw.x >> 16);
    int c2 = (int)(raw.y & 0xFFFFu), c3 = (int)(raw.y >> 16);
    if (c0 < m0) { m0 = c0; a0 = i; }
    if (c1 < m1) { m1 = c1; a1 = i; }
    if (c2 < m2) { m2 = c2; a2 = i; }
    if (c3 < m3) { m3 = c3; a3 = i; }
  }
  // parallel claim (== reverse-order serial CR: max col wins each row)
  atomicMax(&claim[a0], col0 + 0);
  atomicMax(&claim[a1], col0 + 1);
  atomicMax(&claim[a2], col0 + 2);
  atomicMax(&claim[a3], col0 + 3);
  int p[4];   // col -> row (1-based, 0 = free)
  int vv[4];  // packed: col - (v<<8)
  p[0] = (claim[a0] == col0 + 0) ? a0 + 1 : 0;
  p[1] = (claim[a1] == col0 + 1) ? a1 + 1 : 0;
  p[2] = (claim[a2] == col0 + 2) ? a2 + 1 : 0;
  p[3] = (claim[a3] == col0 + 3) ? a3 + 1 : 0;
  if (p[0]) x_lds[a0] = col0 + 0;
  if (p[1]) x_lds[a1] = col0 + 1;
  if (p[2]) x_lds[a2] = col0 + 2;
  if (p[3]) x_lds[a3] = col0 + 3;
  vv[0] = (col0 + 0) - (m0 << 8);
  vv[1] = (col0 + 1) - (m1 << 8);
  vv[2] = (col0 + 2) - (m2 << 8);
  vv[3] = (col0 + 3) - (m3 << 8);

  // ---- augmenting row reduction (lap.py semantics; capped => always safe) ----
  {
    int cnt = compact_free(x_lds, Fl, lane);
    int k = 0, steps = 0;
    while (k < cnt && steps < 4096) {
      ++steps;
      int i = Fl[k]; ++k;                         // uniform broadcast read
      uint2 raw = *reinterpret_cast<const uint2*>(&Cs[(size_t)i * NN + col0]);
      unsigned key[4];
      key[0] = (unsigned)((int)((raw.x & 0xFFFFu) << 8) + vv[0]);
      key[1] = (unsigned)((int)((raw.x >> 8) & 0x00FFFF00u) + vv[1]);
      key[2] = (unsigned)((int)((raw.y & 0xFFFFu) << 8) + vv[2]);
      key[3] = (unsigned)((int)((raw.y >> 8) & 0x00FFFF00u) + vv[3]);
      unsigned lo01 = key[0] < key[1] ? key[0] : key[1];
      unsigned lo23 = key[2] < key[3] ? key[2] : key[3];
      unsigned loc = lo01 < lo23 ? lo01 : lo23;
      unsigned K1 = (unsigned)readlane_i((int)wave_min_u32(loc), 63);
      int j1 = (int)(K1 & 0xFFu);
      // second min: mask j1's slot
      if (lane == (j1 >> 2)) {
        int qq = j1 & 3;
        if (qq == 0) key[0] = 0xFFFFFFFFu;
        else if (qq == 1) key[1] = 0xFFFFFFFFu;
        else if (qq == 2) key[2] = 0xFFFFFFFFu;
        else key[3] = 0xFFFFFFFFu;
      }
      lo01 = key[0] < key[1] ? key[0] : key[1];
      lo23 = key[2] < key[3] ? key[2] : key[3];
      loc = lo01 < lo23 ? lo01 : lo23;
      unsigned K2 = (unsigned)readlane_i((int)wave_min_u32(loc), 63);
      unsigned u1v = K1 >> 8, u2v = K2 >> 8;
      bool lower = u1v < u2v;
      int owner1 = readlane_i(sel4i(p, j1 & 3), j1 >> 2) - 1;  // y[j1]
      int jf, i0;
      if (lower) {
        int dq = (int)(u2v - u1v) << 8;   // v[j1] -= (u2-u1)
        if (lane == (j1 >> 2)) {
          int qq = j1 & 3;
          if (qq == 0) vv[0] += dq;
          else if (qq == 1) vv[1] += dq;
          else if (qq == 2) vv[2] += dq;
          else vv[3] += dq;
        }
        jf = j1; i0 = owner1;
      } else if (owner1 >= 0) {
        jf = (int)(K2 & 0xFFu);
        i0 = readlane_i(sel4i(p, jf & 3), jf >> 2) - 1;
      } else {
        jf = j1; i0 = -1;
      }
      if (lane == (jf >> 2)) set4i(p, jf & 3, i + 1);
      if (lane == 0) {
        x_lds[i] = jf;
        if (i0 >= 0) x_lds[i0] = -1;
      }
      if (i0 >= 0) {
        if (lower) { --k; if (lane == 0) Fl[k] = i0; }
        else if (cnt < 1024) { if (lane == 0) Fl[cnt] = i0; ++cnt; }
      }
    }
  }

  // ---- init u[] from final init duals; rebuild free list ----
  claim[col0 + 0] = ((col0 + 0) - vv[0]) >> 8;  // v[j] broadcast
  claim[col0 + 1] = ((col0 + 1) - vv[1]) >> 8;
  claim[col0 + 2] = ((col0 + 2) - vv[2]) >> 8;
  claim[col0 + 3] = ((col0 + 3) - vv[3]) >> 8;
  {
    int4 xr = *reinterpret_cast<const int4*>(&x_lds[col0]);
    u_lds[col0 + 0] = (xr.x >= 0) ? ((int)Cs[(size_t)(col0 + 0) * NN + xr.x] - claim[xr.x]) : 0;
    u_lds[col0 + 1] = (xr.y >= 0) ? ((int)Cs[(size_t)(col0 + 1) * NN + xr.y] - claim[xr.y]) : 0;
    u_lds[col0 + 2] = (xr.z >= 0) ? ((int)Cs[(size_t)(col0 + 2) * NN + xr.z] - claim[xr.z]) : 0;
    u_lds[col0 + 3] = (xr.w >= 0) ? ((int)Cs[(size_t)(col0 + 3) * NN + xr.w] - claim[xr.w]) : 0;
  }
  int nfree = compact_free(x_lds, Fl, lane);

  // ---- Dijkstra augmentation for remaining free rows (verified R6 body) ----
  for (int idx = 0; idx < nfree; ++idx) {
    int i = Fl[idx] + 1;  // 1-based phase row
    unsigned key[4] = {0xFFFFFFFFu, 0xFFFFFFFFu, 0xFFFFFFFFu, 0xFFFFFFFFu};
    int way[4] = {-1, -1, -1, -1};
    int usedm = 0;
    int Delta = 0;
    int j0 = -1;
    int u_i0 = 0;
    int row = i - 1;
    uint2 raw = *reinterpret_cast<const uint2*>(&Cs[(size_t)row * NN + col0]);
    int jf;

    while (true) {
      int t0s8 = (Delta - u_i0) << 8;
      int cs[4];
      cs[0] = (int)((raw.x & 0xFFFFu) << 8);
      cs[1] = (int)((raw.x >> 8) & 0x00FFFF00u);
      cs[2] = (int)((raw.y & 0xFFFFu) << 8);
      cs[3] = (int)((raw.y >> 8) & 0x00FFFF00u);
      #pragma unroll
      for (int q = 0; q < 4; ++q) {
        unsigned nk = (unsigned)(t0s8 + cs[q] + vv[q]);  // (dist<<8)|col, exact
        if (nk < key[q]) { key[q] = nk; way[q] = j0; }
      }
      unsigned c0 = (usedm & 1) ? 0xFFFFFFFFu : key[0];
      unsigned c1 = (usedm & 2) ? 0xFFFFFFFFu : key[1];
      unsigned c2 = (usedm & 4) ? 0xFFFFFFFFu : key[2];
      unsigned c3 = (usedm & 8) ? 0xFFFFFFFFu : key[3];
      unsigned loc = c0 < c1 ? c0 : c1;
      unsigned l2 = c2 < c3 ? c2 : c3;
      loc = loc < l2 ? loc : l2;
      unsigned K = (unsigned)readlane_i((int)wave_min_u32(loc), 63);
      int j1 = (int)(K & 0xFFu);
      Delta = (int)(K >> 8);
      int pnext = readlane_i(sel4i(p, j1 & 3), j1 >> 2);
      if (pnext == 0) { jf = j1; break; }
      row = pnext - 1;
      raw = *reinterpret_cast<const uint2*>(&Cs[(size_t)row * NN + col0]);
      u_i0 = u_lds[row];
      if (lane == (j1 >> 2)) usedm |= 1 << (j1 & 3);
      j0 = j1;
    }

    // phase-end dual updates (used cols only; jf excluded) — exact int
    #pragma unroll
    for (int q = 0; q < 4; ++q) {
      if ((usedm >> q) & 1) {
        int dd = Delta - (int)(key[q] >> 8);
        vv[q] += dd << 8;                 // v[q] -= dd
        u_lds[p[q] - 1] += dd;            // rows distinct across lanes
      }
    }
    if (lane == 0) u_lds[i - 1] = Delta;  // phase row: u was 0

    // augmentation walk (uniform, readlane broadcasts)
    int j = jf;
    while (true) {
      int w = readlane_i(sel4i(way, j & 3), j >> 2);  // way[j]
      int newv;
      if (w < 0) newv = i;
      else newv = readlane_i(sel4i(p, w & 3), w >> 2);  // old p[way[j]]
      if (lane == (j >> 2)) set4i(p, j & 3, newv);
      if (w < 0) break;
      j = w;
    }
  }
  // col4row[p[j]-1] = j
  #pragma unroll
  for (int q = 0; q < 4; ++q)
    tgt[(size_t)b * NN + (p[q] - 1)] = col0 + q;
}

// ---------------- 4. fused log-softmax + NLL (one wave per row) ----------------
__global__ __launch_bounds__(256) void nll_kernel(const float* __restrict__ cosm,
                                                  const float* __restrict__ selfm,
                                                  const int* __restrict__ tgt,
                                                  float* __restrict__ nll) {
  int lane = threadIdx.x & 63, wid = threadIdx.x >> 6;
  int row = blockIdx.x * 4 + wid;
  int r = row & (NN - 1);
  const float* crow = cosm + (size_t)row * NN;
  const float* srow = selfm + (size_t)row * NN;
  float xc[4], xs[4];
  float m = -INFINITY;
  #pragma unroll
  for (int q = 0; q < 4; ++q) {
    int j = lane + 64 * q;
    xc[q] = crow[j];
    xs[q] = (j == r) ? -INFINITY : srow[j];
    m = fmaxf(m, fmaxf(xc[q], xs[q]));
  }
  #pragma unroll
  for (int off = 32; off; off >>= 1) m = fmaxf(m, __shfl_xor(m, off));
  float s = 0.f;
  #pragma unroll
  for (int q = 0; q < 4; ++q) {
    s += expf(xc[q] - m);
    s += (xs[q] == -INFINITY) ? 0.f : expf(xs[q] - m);
  }
  #pragma unroll
  for (int off = 32; off; off >>= 1) s += __shfl_xor(s, off);
  if (lane == 0) {
    float lse = m + logf(s);
    nll[row] = lse - crow[tgt[row]];
  }
}

// ---------------- 5. deterministic mean reduce ----------------
__global__ __launch_bounds__(256) void reduce_kernel(const float* __restrict__ nll,
                                                     float* __restrict__ out) {
  __shared__ float sm[256];
  int t = threadIdx.x;
  float s = 0.f;
  for (int i = t; i < NROWS; i += 256) s += nll[i];
  sm[t] = s;
  __syncthreads();
  for (int st = 128; st; st >>= 1) {
    if (t < st) sm[t] += sm[t + st];
    __syncthreads();
  }
  if (t == 0) out[0] = sm[0] / (float)NROWS;
}

extern "C" void kernel_launch(void* const* d_in, const int* in_sizes, int n_in,
                              void* d_out, int out_size, void* d_ws, size_t ws_size,
                              hipStream_t stream) {
  const float* inputs = (const float*)d_in[0];
  const float* targets = (const float*)d_in[1];
  float* ws = (float*)d_ws;
  float* ipn = ws;
  float* tgn = ipn + (size_t)BB * NN * DD;
  float* cosm = tgn + (size_t)BB * NN * DD;
  float* selfm = cosm + (size_t)BB * NN * NN;
  int* tgt = (int*)(selfm + (size_t)BB * NN * NN);
  float* nll = (float*)(tgt + BB * NN);

  norm_kernel<<<2 * NROWS / 4, 256, 0, stream>>>(inputs, targets, ipn, tgn);
  gemm_kernel<<<dim3(16, BB, 2), 256, 0, stream>>>(ipn, tgn, cosm, selfm);
  hungarian_kernel<<<BB, 64, 0, stream>>>(cosm, tgt);
  nll_kernel<<<NROWS / 4, 256, 0, stream>>>(cosm, selfm, tgt, nll);
  reduce_kernel<<<1, 256, 0, stream>>>(nll, (float*)d_out);
}

// Round 8
// 1206.840 us; speedup vs baseline: 2.2616x; 2.2616x over previous
//
#include <hip/hip_runtime.h>
#include <math.h>

#define BB 128
#define NN 256
#define DD 64
constexpr int NROWS = BB * NN; // 32768

// ---------------- 1. L2 normalize (one wave per row of 64) ----------------
__global__ __launch_bounds__(256) void norm_kernel(const float* __restrict__ inp,
                                                   const float* __restrict__ tgin,
                                                   float* __restrict__ ipn,
                                                   float* __restrict__ tgn) {
  int wid = threadIdx.x >> 6;
  int lane = threadIdx.x & 63;
  int row = blockIdx.x * 4 + wid;   // 0 .. 2*NROWS-1
  const float* src;
  float* dst;
  int r = row;
  if (row < NROWS) { src = inp; dst = ipn; }
  else { src = tgin; dst = tgn; r = row - NROWS; }
  float x = src[(size_t)r * DD + lane];
  float s = x * x;
  #pragma unroll
  for (int off = 32; off; off >>= 1) s += __shfl_xor(s, off);
  float nrm = sqrtf(s);
  float scale = 1.0f / fmaxf(nrm, 1e-12f);
  dst[(size_t)r * DD + lane] = x * scale;
}

// ---------------- 2. batched fp32 GEMM: 64x64 tile, K=64 ----------------
__global__ __launch_bounds__(256) void gemm_kernel(const float* __restrict__ ipn,
                                                   const float* __restrict__ tgn,
                                                   float* __restrict__ cosm,
                                                   float* __restrict__ selfm) {
  __shared__ float As[64 * 64];  // [k][row] transposed
  __shared__ float Bs[64 * 64];
  int b = blockIdx.y;
  int ti = (blockIdx.x >> 2) * 64;
  int tj = (blockIdx.x & 3) * 64;
  const float* A = ipn + (size_t)b * NN * DD + (size_t)ti * DD;
  const float* Bm = (blockIdx.z ? ipn : tgn) + (size_t)b * NN * DD + (size_t)tj * DD;
  float* Out = (blockIdx.z ? selfm : cosm) + (size_t)b * NN * NN;
  int t = threadIdx.x;
  #pragma unroll
  for (int i = 0; i < 4; ++i) {
    int f4 = t + 256 * i;
    int row = f4 >> 4;
    int k0 = (f4 & 15) << 2;
    float4 a = reinterpret_cast<const float4*>(A)[f4];
    float4 v = reinterpret_cast<const float4*>(Bm)[f4];
    As[(k0 + 0) * 64 + row] = a.x; As[(k0 + 1) * 64 + row] = a.y;
    As[(k0 + 2) * 64 + row] = a.z; As[(k0 + 3) * 64 + row] = a.w;
    Bs[(k0 + 0) * 64 + row] = v.x; Bs[(k0 + 1) * 64 + row] = v.y;
    Bs[(k0 + 2) * 64 + row] = v.z; Bs[(k0 + 3) * 64 + row] = v.w;
  }
  __syncthreads();
  int tx = t & 15, ty = t >> 4;
  float acc[4][4] = {};
  #pragma unroll 8
  for (int k = 0; k < 64; ++k) {
    float4 av = *reinterpret_cast<const float4*>(&As[k * 64 + ty * 4]);
    float4 bv = *reinterpret_cast<const float4*>(&Bs[k * 64 + tx * 4]);
    float ar[4] = {av.x, av.y, av.z, av.w};
    float br[4] = {bv.x, bv.y, bv.z, bv.w};
    #pragma unroll
    for (int r = 0; r < 4; ++r)
      #pragma unroll
      for (int c = 0; c < 4; ++c)
        acc[r][c] = fmaf(ar[r], br[c], acc[r][c]);
  }
  #pragma unroll
  for (int r = 0; r < 4; ++r) {
    float4 o = {acc[r][0], acc[r][1], acc[r][2], acc[r][3]};
    *reinterpret_cast<float4*>(&Out[(size_t)(ti + ty * 4 + r) * NN + tj + tx * 4]) = o;
  }
}

// ---------------- 3. JV LSAP: CR init + Dijkstra, one wave/batch, exact int ----------------
__device__ __forceinline__ int sel4i(const int a[4], int q) {
  int r = a[0];
  if (q == 1) r = a[1];
  else if (q == 2) r = a[2];
  else if (q == 3) r = a[3];
  return r;
}
__device__ __forceinline__ void set4i(int a[4], int q, int v) {
  if (q == 0) a[0] = v;
  else if (q == 1) a[1] = v;
  else if (q == 2) a[2] = v;
  else a[3] = v;
}
__device__ __forceinline__ int readlane_i(int x, int l) {
  return __builtin_amdgcn_readlane(x, l);
}
// 64-lane unsigned min via DPP; global min lands in lane 63.
__device__ __forceinline__ unsigned wave_min_u32(unsigned x) {
  unsigned t;
  #define DPP_STEP(ctrl)                                                        \
    t = (unsigned)__builtin_amdgcn_update_dpp((int)x, (int)x, ctrl, 0xF, 0xF,   \
                                              false);                           \
    x = (t < x) ? t : x;
  DPP_STEP(0x111)  // row_shr:1
  DPP_STEP(0x112)  // row_shr:2
  DPP_STEP(0x114)  // row_shr:4
  DPP_STEP(0x118)  // row_shr:8
  DPP_STEP(0x142)  // row_bcast:15
  DPP_STEP(0x143)  // row_bcast:31
  #undef DPP_STEP
  return x;
}
// deterministic compaction of {i : x[i] < 0} into Fl; returns count
__device__ __forceinline__ int compact_free(const int* x_lds, int* Fl, int lane) {
  int row0 = lane * 4;
  int4 xv = *reinterpret_cast<const int4*>(&x_lds[row0]);
  int f0 = (xv.x < 0), f1 = (xv.y < 0), f2 = (xv.z < 0), f3 = (xv.w < 0);
  int cnt = f0 + f1 + f2 + f3;
  int sc = cnt;
  #pragma unroll
  for (int off = 1; off < 64; off <<= 1) {
    int t = __shfl_up(sc, off);
    if (lane >= off) sc += t;
  }
  int pos = sc - cnt;  // exclusive prefix
  if (f0) { Fl[pos] = row0 + 0; pos++; }
  if (f1) { Fl[pos] = row0 + 1; pos++; }
  if (f2) { Fl[pos] = row0 + 2; pos++; }
  if (f3) { Fl[pos] = row0 + 3; pos++; }
  return readlane_i(sc, 63);
}

__global__ __launch_bounds__(64) void hungarian_kernel(const float* __restrict__ cosm,
                                                       int* __restrict__ tgt) {
  const int b = blockIdx.x;
  const float* __restrict__ C = cosm + (size_t)b * NN * NN;
  __shared__ unsigned short Cs[NN * NN];  // 128 KiB u16 fixed-point cost
  __shared__ int u_lds[NN];               // row duals (all 0 after CR init)
  __shared__ int x_lds[NN];               // row -> col (-1 = free)
  __shared__ int claim[NN];               // CR claim per row
  __shared__ int Fl[NN];                  // free-row list
  const int lane = threadIdx.x;           // 0..63
  const int col0 = lane * 4;

  // ---- stage: C_int = clamp(round((1 - cos) * 32768), 0, 65535) ----
  const float4* Cf4 = reinterpret_cast<const float4*>(C);
  #pragma unroll 4
  for (int it = 0; it < NN * NN / 4 / 64; ++it) {
    float4 f = Cf4[it * 64 + lane];
    unsigned u0 = __float2uint_rn(fmaxf(32768.f - f.x * 32768.f, 0.f));
    unsigned u1 = __float2uint_rn(fmaxf(32768.f - f.y * 32768.f, 0.f));
    unsigned u2 = __float2uint_rn(fmaxf(32768.f - f.z * 32768.f, 0.f));
    unsigned u3 = __float2uint_rn(fmaxf(32768.f - f.w * 32768.f, 0.f));
    u0 = u0 > 65535u ? 65535u : u0;
    u1 = u1 > 65535u ? 65535u : u1;
    u2 = u2 > 65535u ? 65535u : u2;
    u3 = u3 > 65535u ? 65535u : u3;
    uint2 packed;
    packed.x = u0 | (u1 << 16);
    packed.y = u2 | (u3 << 16);
    *reinterpret_cast<uint2*>(&Cs[(it * 64 + lane) * 4]) = packed;
  }
  {
    int4 mi = {-1, -1, -1, -1};
    int4 zi = {0, 0, 0, 0};
    *reinterpret_cast<int4*>(&x_lds[col0]) = mi;
    *reinterpret_cast<int4*>(&claim[col0]) = mi;
    *reinterpret_cast<int4*>(&u_lds[col0]) = zi;   // CR leaves all u = 0
  }

  // ---- column reduction: v[j] = min_i c[i][j] (strict < => lowest row) ----
  int m0 = 0x7FFFFFFF, m1 = 0x7FFFFFFF, m2 = 0x7FFFFFFF, m3 = 0x7FFFFFFF;
  int a0 = 0, a1 = 0, a2 = 0, a3 = 0;
  #pragma unroll 4
  for (int i = 0; i < NN; ++i) {
    uint2 raw = *reinterpret_cast<const uint2*>(&Cs[(size_t)i * NN + col0]);
    int c0 = (int)(raw.x & 0xFFFFu), c1 = (int)(raw.x >> 16);
    int c2 = (int)(raw.y & 0xFFFFu), c3 = (int)(raw.y >> 16);
    if (c0 < m0) { m0 = c0; a0 = i; }
    if (c1 < m1) { m1 = c1; a1 = i; }
    if (c2 < m2) { m2 = c2; a2 = i; }
    if (c3 < m3) { m3 = c3; a3 = i; }
  }
  // parallel claim: each argmin row taken by the max col wanting it
  atomicMax(&claim[a0], col0 + 0);
  atomicMax(&claim[a1], col0 + 1);
  atomicMax(&claim[a2], col0 + 2);
  atomicMax(&claim[a3], col0 + 3);
  int p[4];   // col -> row (1-based, 0 = free)
  int vv[4];  // packed: col - (v<<8)
  p[0] = (claim[a0] == col0 + 0) ? a0 + 1 : 0;
  p[1] = (claim[a1] == col0 + 1) ? a1 + 1 : 0;
  p[2] = (claim[a2] == col0 + 2) ? a2 + 1 : 0;
  p[3] = (claim[a3] == col0 + 3) ? a3 + 1 : 0;
  if (p[0]) x_lds[a0] = col0 + 0;
  if (p[1]) x_lds[a1] = col0 + 1;
  if (p[2]) x_lds[a2] = col0 + 2;
  if (p[3]) x_lds[a3] = col0 + 3;
  vv[0] = (col0 + 0) - (m0 << 8);
  vv[1] = (col0 + 1) - (m1 << 8);
  vv[2] = (col0 + 2) - (m2 << 8);
  vv[3] = (col0 + 3) - (m3 << 8);
  // claimed rows: c[a][col] - v[col] = 0 -> u stays 0; invariant holds.

  int nfree = compact_free(x_lds, Fl, lane);

  // ---- Dijkstra augmentation for free rows (verified R6 body) ----
  for (int idx = 0; idx < nfree; ++idx) {
    int i = Fl[idx] + 1;  // 1-based phase row
    unsigned key[4] = {0xFFFFFFFFu, 0xFFFFFFFFu, 0xFFFFFFFFu, 0xFFFFFFFFu};
    int way[4] = {-1, -1, -1, -1};
    int usedm = 0;
    int Delta = 0;
    int j0 = -1;
    int u_i0 = 0;
    int row = i - 1;
    uint2 raw = *reinterpret_cast<const uint2*>(&Cs[(size_t)row * NN + col0]);
    int jf;

    while (true) {
      int t0s8 = (Delta - u_i0) << 8;
      int cs[4];
      cs[0] = (int)((raw.x & 0xFFFFu) << 8);
      cs[1] = (int)((raw.x >> 8) & 0x00FFFF00u);
      cs[2] = (int)((raw.y & 0xFFFFu) << 8);
      cs[3] = (int)((raw.y >> 8) & 0x00FFFF00u);
      #pragma unroll
      for (int q = 0; q < 4; ++q) {
        unsigned nk = (unsigned)(t0s8 + cs[q] + vv[q]);  // (dist<<8)|col, exact
        if (nk < key[q]) { key[q] = nk; way[q] = j0; }
      }
      unsigned c0 = (usedm & 1) ? 0xFFFFFFFFu : key[0];
      unsigned c1 = (usedm & 2) ? 0xFFFFFFFFu : key[1];
      unsigned c2 = (usedm & 4) ? 0xFFFFFFFFu : key[2];
      unsigned c3 = (usedm & 8) ? 0xFFFFFFFFu : key[3];
      unsigned loc = c0 < c1 ? c0 : c1;
      unsigned l2 = c2 < c3 ? c2 : c3;
      loc = loc < l2 ? loc : l2;
      unsigned K = (unsigned)readlane_i((int)wave_min_u32(loc), 63);
      int j1 = (int)(K & 0xFFu);
      Delta = (int)(K >> 8);
      int pnext = readlane_i(sel4i(p, j1 & 3), j1 >> 2);
      if (pnext == 0) { jf = j1; break; }
      row = pnext - 1;
      raw = *reinterpret_cast<const uint2*>(&Cs[(size_t)row * NN + col0]);
      u_i0 = u_lds[row];
      if (lane == (j1 >> 2)) usedm |= 1 << (j1 & 3);
      j0 = j1;
    }

    // phase-end dual updates (used cols only; jf excluded) — exact int
    #pragma unroll
    for (int q = 0; q < 4; ++q) {
      if ((usedm >> q) & 1) {
        int dd = Delta - (int)(key[q] >> 8);
        vv[q] += dd << 8;                 // v[q] -= dd
        u_lds[p[q] - 1] += dd;            // rows distinct across lanes
      }
    }
    if (lane == 0) u_lds[i - 1] = Delta;  // phase row: u was 0

    // augmentation walk (uniform, readlane broadcasts)
    int j = jf;
    while (true) {
      int w = readlane_i(sel4i(way, j & 3), j >> 2);  // way[j]
      int newv;
      if (w < 0) newv = i;
      else newv = readlane_i(sel4i(p, w & 3), w >> 2);  // old p[way[j]]
      if (lane == (j >> 2)) set4i(p, j & 3, newv);
      if (w < 0) break;
      j = w;
    }
  }
  // col4row[p[j]-1] = j
  #pragma unroll
  for (int q = 0; q < 4; ++q)
    tgt[(size_t)b * NN + (p[q] - 1)] = col0 + q;
}

// ---------------- 4. fused log-softmax + NLL (one wave per row) ----------------
__global__ __launch_bounds__(256) void nll_kernel(const float* __restrict__ cosm,
                                                  const float* __restrict__ selfm,
                                                  const int* __restrict__ tgt,
                                                  float* __restrict__ nll) {
  int lane = threadIdx.x & 63, wid = threadIdx.x >> 6;
  int row = blockIdx.x * 4 + wid;
  int r = row & (NN - 1);
  const float* crow = cosm + (size_t)row * NN;
  const float* srow = selfm + (size_t)row * NN;
  float xc[4], xs[4];
  float m = -INFINITY;
  #pragma unroll
  for (int q = 0; q < 4; ++q) {
    int j = lane + 64 * q;
    xc[q] = crow[j];
    xs[q] = (j == r) ? -INFINITY : srow[j];
    m = fmaxf(m, fmaxf(xc[q], xs[q]));
  }
  #pragma unroll
  for (int off = 32; off; off >>= 1) m = fmaxf(m, __shfl_xor(m, off));
  float s = 0.f;
  #pragma unroll
  for (int q = 0; q < 4; ++q) {
    s += expf(xc[q] - m);
    s += (xs[q] == -INFINITY) ? 0.f : expf(xs[q] - m);
  }
  #pragma unroll
  for (int off = 32; off; off >>= 1) s += __shfl_xor(s, off);
  if (lane == 0) {
    float lse = m + logf(s);
    nll[row] = lse - crow[tgt[row]];
  }
}

// ---------------- 5. deterministic mean reduce ----------------
__global__ __launch_bounds__(256) void reduce_kernel(const float* __restrict__ nll,
                                                     float* __restrict__ out) {
  __shared__ float sm[256];
  int t = threadIdx.x;
  float s = 0.f;
  for (int i = t; i < NROWS; i += 256) s += nll[i];
  sm[t] = s;
  __syncthreads();
  for (int st = 128; st; st >>= 1) {
    if (t < st) sm[t] += sm[t + st];
    __syncthreads();
  }
  if (t == 0) out[0] = sm[0] / (float)NROWS;
}

extern "C" void kernel_launch(void* const* d_in, const int* in_sizes, int n_in,
                              void* d_out, int out_size, void* d_ws, size_t ws_size,
                              hipStream_t stream) {
  const float* inputs = (const float*)d_in[0];
  const float* targets = (const float*)d_in[1];
  float* ws = (float*)d_ws;
  float* ipn = ws;
  float* tgn = ipn + (size_t)BB * NN * DD;
  float* cosm = tgn + (size_t)BB * NN * DD;
  float* selfm = cosm + (size_t)BB * NN * NN;
  int* tgt = (int*)(selfm + (size_t)BB * NN * NN);
  float* nll = (float*)(tgt + BB * NN);

  norm_kernel<<<2 * NROWS / 4, 256, 0, stream>>>(inputs, targets, ipn, tgn);
  gemm_kernel<<<dim3(16, BB, 2), 256, 0, stream>>>(ipn, tgn, cosm, selfm);
  hungarian_kernel<<<BB, 64, 0, stream>>>(cosm, tgt);
  nll_kernel<<<NROWS / 4, 256, 0, stream>>>(cosm, selfm, tgt, nll);
  reduce_kernel<<<1, 256, 0, stream>>>(nll, (float*)d_out);
}